// Round 10
// baseline (322.320 us; speedup 1.0000x reference)
//
#include <hip/hip_runtime.h>
#include <hip/hip_bf16.h>
#include <math.h>

// Problem constants
#define B_    8
#define C_    64
#define H_    64
#define W_    64
#define NUM_EMBED 8192
#define DIMS  64
#define N_TOK (B_ * H_ * W_)           // 32768
#define N_ELEM (B_ * C_ * H_ * W_)     // 2097152

typedef short v8s __attribute__((ext_vector_type(8)));   // 8 bf16 = 4 VGPR
typedef float v4f __attribute__((ext_vector_type(4)));   // MFMA acc

#define MARGIN 0.011f      // empirical bf16 margin, passed rounds 0-4
#define UB_ULP 0.008f      // max up-rounding of the u16 monotone bound

// ---- helpers ---------------------------------------------------------------
__device__ __forceinline__ short bf16_rne(float x) {
    unsigned u = __float_as_uint(x);
    unsigned r = (u + 0x7FFFu + ((u >> 16) & 1u)) >> 16;
    return (short)r;
}
// monotone float->u32 (order-preserving, incl. negatives)
__device__ __forceinline__ unsigned mono(float f) {
    int b = __float_as_int(f);
    return (unsigned)(b ^ ((b >> 31) | 0x80000000));
}
__device__ __forceinline__ float demono(unsigned u) {
    int b = (u >> 31) ? (int)(u ^ 0x80000000u) : (int)~u;
    return __int_as_float(b);
}
__device__ __forceinline__ unsigned short ub16(float x) {
    // 16-bit monotone upper bound (round UP)
    return (unsigned short)((mono(x) + 0xFFFFu) >> 16);
}

// ---------------------------------------------------------------------------
// P1: inverse row norms of embedding. 4 rows/block, one wave per row.
// ---------------------------------------------------------------------------
__global__ void invnorm_kernel(const float* __restrict__ emb, float* __restrict__ invn) {
    int wave = threadIdx.x >> 6;
    int lane = threadIdx.x & 63;
    int row  = blockIdx.x * 4 + wave;
    float v = emb[row * DIMS + lane];
    float s = v * v;
    #pragma unroll
    for (int off = 1; off < 64; off <<= 1) s += __shfl_xor(s, off, 64);
    if (lane == 0) invn[row] = 1.0f / sqrtf(s);
}

// ---------------------------------------------------------------------------
// P2: build B fragments: en_frag[(ct*2+st)*64 + lane] = 8 bf16 of
//     en[code = ct*16 + (lane&15)][k = st*32 + (lane>>4)*8 + j]
// ---------------------------------------------------------------------------
__global__ void en_frag_kernel(const float* __restrict__ emb, const float* __restrict__ invn,
                               v8s* __restrict__ ef) {
    int ch = blockIdx.x * 256 + threadIdx.x;      // 0..65535
    int l  = ch & 63;
    int st = (ch >> 6) & 1;
    int ct = ch >> 7;
    int code = ct * 16 + (l & 15);
    int kb   = st * 32 + ((l >> 4) & 3) * 8;
    float rn = invn[code];
    v8s o;
    #pragma unroll
    for (int j = 0; j < 8; ++j) o[j] = bf16_rne(emb[code * DIMS + kb + j] * rn);
    ef[ch] = o;
}

// ---------------------------------------------------------------------------
// P3: z -> A fragments (normalized bf16). Block = one (b,h) row = 64 tokens.
// ---------------------------------------------------------------------------
__global__ __launch_bounds__(256)
void z_prep_kernel(const float* __restrict__ z, v8s* __restrict__ af) {
    __shared__ float zs[64][65];   // [c][token_local], +1 pad
    __shared__ float part[4][64];
    __shared__ float rn[64];
    const int tid = threadIdx.x;
    const int w   = tid & 63;
    const int cg  = tid >> 6;
    const int bh  = blockIdx.x;            // 0..511
    const int b   = bh >> 6, h = bh & 63;

    const float* zb = z + (size_t)b * (C_ * H_ * W_) + h * W_;
    float ss = 0.f;
    #pragma unroll
    for (int cc = 0; cc < 16; ++cc) {
        int c = cg * 16 + cc;
        float v = zb[c * (H_ * W_) + w];
        zs[c][w] = v;
        ss += v * v;
    }
    part[cg][w] = ss;
    __syncthreads();
    if (tid < 64) {
        float s = part[0][tid] + part[1][tid] + part[2][tid] + part[3][tid];
        rn[tid] = 1.0f / sqrtf(s);
    }
    __syncthreads();

    // A fragments: 512 chunks (4 mtiles x 2 ksteps x 64 lanes), 2 per thread
    #pragma unroll
    for (int ii = 0; ii < 2; ++ii) {
        int ch  = tid + ii * 256;
        int mtl = ch >> 7;
        int st  = (ch >> 6) & 1;
        int l   = ch & 63;
        int tloc = mtl * 16 + (l & 15);
        int kb   = st * 32 + ((l >> 4) & 3) * 8;
        float rr = rn[tloc];
        v8s o;
        #pragma unroll
        for (int j = 0; j < 8; ++j) o[j] = bf16_rne(zs[kb + j][tloc] * rr);
        af[(size_t)((bh * 4 + mtl) * 2 + st) * 64 + l] = o;
    }
}

// ---------------------------------------------------------------------------
// GEMM config (pass1 = the only GEMM): unchanged from round 9 (RT=2, no
// spill, XCD-local bm, 16-way split, per-64-code upper-bound export).
// ---------------------------------------------------------------------------
#define RT 2
#define SPLITS 16
#define TILES_PER_BLOCK 32
#define CHUNK_TILES 8
#define CHUNKS (TILES_PER_BLOCK / CHUNK_TILES)   // 4
#define SUBT 4                          // tiles per bound group (64 codes)
#define NSUB (CHUNK_TILES / SUBT)       // 2 sub-chunks per LDS chunk
#define NCHUNK_TOT 128                  // 16 splits * 4 chunks * 2 sub = 128

__global__ __launch_bounds__(512, 8)
void pass1_kernel(const v8s* __restrict__ af, const v8s* __restrict__ ef,
                  unsigned short* __restrict__ cmax) {
    __shared__ v8s lds[CHUNK_TILES * 2 * 64];   // 16 KB
    const int tid  = threadIdx.x;
    const int lane = tid & 63;
    const int wave = tid >> 6;
    const int bm    = blockIdx.x & 127;         // low bits -> XCD locality
    const int split = blockIdx.x >> 7;
    const int tile0 = split * TILES_PER_BLOCK;

    const int mtb = bm * 16 + wave * RT;        // first m-tile of this wave
    v8s a[RT][2];
    #pragma unroll
    for (int r = 0; r < RT; ++r)
        #pragma unroll
        for (int s = 0; s < 2; ++s)
            a[r][s] = af[(size_t)((mtb + r) * 2 + s) * 64 + lane];

    const float4* gsrc = (const float4*)(ef + (size_t)tile0 * 2 * 64);
    float4* lf = (float4*)lds;
    float4 pre[2];
    pre[0] = gsrc[tid];
    pre[1] = gsrc[tid + 512];

    for (int c = 0; c < CHUNKS; ++c) {
        __syncthreads();
        lf[tid]       = pre[0];
        lf[tid + 512] = pre[1];
        if (c + 1 < CHUNKS) {
            const float4* nx = gsrc + (size_t)(c + 1) * 1024;
            pre[0] = nx[tid];
            pre[1] = nx[tid + 512];
        }
        __syncthreads();

        #pragma unroll
        for (int jj = 0; jj < NSUB; ++jj) {
            v4f mxc[RT];
            #pragma unroll
            for (int r = 0; r < RT; ++r)
                mxc[r] = (v4f){-1e30f, -1e30f, -1e30f, -1e30f};

            #pragma unroll
            for (int j4 = 0; j4 < SUBT; ++j4) {
                const int j = jj * SUBT + j4;
                v8s b0 = lds[(j * 2 + 0) * 64 + lane];
                v8s b1 = lds[(j * 2 + 1) * 64 + lane];
                #pragma unroll
                for (int r = 0; r < RT; ++r) {
                    v4f t = (v4f){0.f, 0.f, 0.f, 0.f};
                    t = __builtin_amdgcn_mfma_f32_16x16x32_bf16(a[r][0], b0, t, 0, 0, 0);
                    t = __builtin_amdgcn_mfma_f32_16x16x32_bf16(a[r][1], b1, t, 0, 0, 0);
                    mxc[r][0] = fmaxf(mxc[r][0], t[0]);
                    mxc[r][1] = fmaxf(mxc[r][1], t[1]);
                    mxc[r][2] = fmaxf(mxc[r][2], t[2]);
                    mxc[r][3] = fmaxf(mxc[r][3], t[3]);
                }
            }

            // sub-chunk end: reduce over 16 code columns, export upper bound
            #pragma unroll
            for (int r = 0; r < RT; ++r)
                #pragma unroll
                for (int i = 0; i < 4; ++i) {
                    float v = mxc[r][i];
                    v = fmaxf(v, __shfl_xor(v, 1, 64));
                    v = fmaxf(v, __shfl_xor(v, 2, 64));
                    v = fmaxf(v, __shfl_xor(v, 4, 64));
                    v = fmaxf(v, __shfl_xor(v, 8, 64));
                    mxc[r][i] = v;
                }
            if ((lane & 15) == 0) {
                const int q   = lane >> 4;
                const int cid = split * (CHUNKS * NSUB) + c * NSUB + jj;
                unsigned short* dst = cmax + (size_t)cid * N_TOK;
                #pragma unroll
                for (int r = 0; r < RT; ++r) {
                    ushort4 v;
                    v.x = ub16(mxc[r][0]);
                    v.y = ub16(mxc[r][1]);
                    v.z = ub16(mxc[r][2]);
                    v.w = ub16(mxc[r][3]);
                    // tokens (mtb+r)*16 + q*4 + {0..3}: one 8 B store
                    *(ushort4*)(dst + (mtb + r) * 16 + q * 4) = v;
                }
            }
        }
    }
}

// ---------------------------------------------------------------------------
// Rescore v2: block = 32 consecutive tokens (half a (b,h) row), 256 threads
// = 4 waves, each wave serially handles 8 tokens. Round-9 lesson: per-wave
// 64-way-split gathers (z channel-strided, cmax cid-strided) dominated at
// 113 us. Now the block stages BOTH coalesced:
//   - z slab [64 c][32 w] loaded channel-coalesced into zsh[c][w] (pad 33)
//   - bounds cmax[cid][tok0..tok0+31] (64 B contiguous per cid) transposed
//     into cms[cid][t] (pad 34 -> qualify reads conflict-free)
// Chunk qualification + exact fp32 rescore loop unchanged (proven logic).
// Grid 1024 -> 16 waves/CU for latency hiding.
// ---------------------------------------------------------------------------
#define RS_TOK 32

__global__ __launch_bounds__(256)
void rescore_kernel(const unsigned short* __restrict__ cmax,
                    const float* __restrict__ z,
                    const float* __restrict__ emb,
                    const float* __restrict__ invn,
                    int* __restrict__ idx, float* __restrict__ idxmap) {
    __shared__ float zsh[64][33];            // [c][w], pad 33
    __shared__ unsigned short cms[128][34];  // [cid][t], pad 34
    const int tid  = threadIdx.x;
    const int lane = tid & 63;
    const int wv   = tid >> 6;
    const int tok0 = blockIdx.x * RS_TOK;
    const int bh   = tok0 >> 6;
    const int b    = bh >> 6, h = bh & 63;
    const int w0   = tok0 & 63;              // 0 or 32

    // stage z: 64 channels x 32 w, channel-coalesced
    {
        const float* zb = z + (size_t)b * (C_ * H_ * W_) + h * W_ + w0;
        const int w = tid & 31;
        const int c0 = tid >> 5;             // 0..7
        #pragma unroll
        for (int it = 0; it < 8; ++it) {
            int c = c0 + it * 8;
            zsh[c][w] = zb[c * (H_ * W_) + w];
        }
    }
    // stage bounds: 128 cids x 32 tokens (64 B contiguous per cid)
    {
        const int t  = tid & 31;
        const int c0 = tid >> 5;             // 0..7
        #pragma unroll
        for (int it = 0; it < 16; ++it) {
            int cid = c0 + it * 8;
            cms[cid][t] = cmax[(size_t)cid * N_TOK + tok0 + t];
        }
    }
    __syncthreads();

    const int g  = lane >> 4;      // row-group 0..3
    const int li = lane & 15;

    for (int tl = wv; tl < RS_TOK; tl += 4) {
        const int token = tok0 + tl;

        // per-token qualification (lane = cid, cid+64); conflict-free reads
        float ub0 = demono(((unsigned)cms[lane][tl]) << 16);
        float ub1 = demono(((unsigned)cms[64 + lane][tl]) << 16);
        float m = fmaxf(ub0, ub1);
        #pragma unroll
        for (int off = 1; off < 64; off <<= 1) m = fmaxf(m, __shfl_xor(m, off, 64));
        const float thrf = m - (MARGIN + UB_ULP);
        unsigned long long q0 = __ballot(ub0 >= thrf);
        unsigned long long q1 = __ballot(ub1 >= thrf);

        // zr: lane's 4 channels of this token, from LDS
        float4 zr;
        zr.x = zsh[li * 4 + 0][tl];
        zr.y = zsh[li * 4 + 1][tl];
        zr.z = zsh[li * 4 + 2][tl];
        zr.w = zsh[li * 4 + 3][tl];

        float bv = -1e30f;
        int   bc = 0x7FFFFFFF;
        #pragma unroll
        for (int half = 0; half < 2; ++half) {
            unsigned long long q = half ? q1 : q0;
            const int cb = half ? 64 : 0;
            while (q) {
                const int cid = cb + (__ffsll(q) - 1);
                q &= q - 1;
                const int rbase = cid * 64;       // first code of sub-chunk
                #pragma unroll
                for (int i = 0; i < 16; ++i) {
                    const int code = rbase + i * 4 + g;
                    const float4 e = ((const float4*)(emb + (size_t)code * DIMS))[li];
                    float s = zr.x * e.x;
                    s = fmaf(zr.y, e.y, s);
                    s = fmaf(zr.z, e.z, s);
                    s = fmaf(zr.w, e.w, s);
                    s += __shfl_xor(s, 1, 64);
                    s += __shfl_xor(s, 2, 64);
                    s += __shfl_xor(s, 4, 64);
                    s += __shfl_xor(s, 8, 64);
                    const float val = s * invn[code];
                    if (val > bv || (val == bv && code < bc)) { bv = val; bc = code; }
                }
            }
        }
        // merge the 4 row-groups (16-lane groups already agree)
        #pragma unroll
        for (int off = 1; off < 64; off <<= 1) {
            float ov = __shfl_xor(bv, off, 64);
            int   oc = __shfl_xor(bc, off, 64);
            if (ov > bv || (ov == bv && oc < bc)) { bv = ov; bc = oc; }
        }
        if (lane == 0) {
            idx[token]    = bc;
            idxmap[token] = (float)bc;
        }
    }
}

// ---------------------------------------------------------------------------
// K3: gather z_q, out = zv + (q - zv), SSE partial, histogram.
// Round-9 lesson applied: per-token emb reads were 64-way gathers; now each
// wave stages its 16 tokens' emb rows into LDS with one coalesced row-load
// each (id is wave-uniform -> broadcast), main loop reads LDS conflict-free.
// ---------------------------------------------------------------------------
__global__ void gather_loss_kernel(const float* __restrict__ z,
                                   const float* __restrict__ emb,
                                   const int* __restrict__ idx,
                                   float* __restrict__ out,
                                   float* __restrict__ partial,
                                   int* __restrict__ hist) {
    __shared__ float eld[64][65];
    __shared__ float red[256];
    const int tid  = threadIdx.x;
    const int lane = tid & 63;   // w
    const int wave = tid >> 6;
    const int bt   = blockIdx.x; // 0..511
    const int b    = bt >> 6;
    const int h    = bt & 63;

    // stage emb rows of this block's 64 tokens (16 per wave, coalesced rows)
    for (int i = 0; i < 16; ++i) {
        const int tl = wave * 16 + i;
        const int id = idx[bt * 64 + tl];
        eld[tl][lane] = emb[(size_t)id * DIMS + lane];
    }
    __syncthreads();

    const long base = (long)b * (C_ * H_ * W_) + h * W_ + lane;

    float sse = 0.f;
    #pragma unroll
    for (int cc = 0; cc < 16; ++cc) {
        const int c = wave * 16 + cc;
        const float q  = eld[lane][c];
        const float zv = z[base + (long)c * (H_ * W_)];
        out[base + (long)c * (H_ * W_)] = zv + (q - zv);  // exact ref expression
        const float d = q - zv;
        sse += d * d;
    }

    red[tid] = sse;
    __syncthreads();
    for (int s = 128; s > 0; s >>= 1) {
        if (tid < s) red[tid] += red[tid + s];
        __syncthreads();
    }
    if (tid == 0) partial[bt] = red[0];
    if (wave == 0) atomicAdd(&hist[idx[bt * 64 + lane]], 1);
}

// ---------------------------------------------------------------------------
// K4: finalize loss + perplexity. One block of 256 threads.
// ---------------------------------------------------------------------------
__global__ void finalize_kernel(const float* __restrict__ partial,
                                const int* __restrict__ hist,
                                float* __restrict__ out_scal) {
    __shared__ double red[256];
    const int tid = threadIdx.x;

    double s = 0.0;
    for (int i = tid; i < 512; i += 256) s += (double)partial[i];
    red[tid] = s;
    __syncthreads();
    for (int st = 128; st > 0; st >>= 1) {
        if (tid < st) red[tid] += red[tid + st];
        __syncthreads();
    }
    const double sse = red[0];
    __syncthreads();

    double e = 0.0;
    for (int k = tid; k < NUM_EMBED; k += 256) {
        float p = (float)hist[k] / (float)N_TOK;
        e += (double)(p * logf(p + 1e-10f));
    }
    red[tid] = e;
    __syncthreads();
    for (int st = 128; st > 0; st >>= 1) {
        if (tid < st) red[tid] += red[tid + st];
        __syncthreads();
    }
    if (tid == 0) {
        out_scal[0] = (float)(1.25 * sse / (double)N_ELEM);
        out_scal[1] = expf(-(float)red[0]);
    }
}

// ---------------------------------------------------------------------------
extern "C" void kernel_launch(void* const* d_in, const int* in_sizes, int n_in,
                              void* d_out, int out_size, void* d_ws, size_t ws_size,
                              hipStream_t stream) {
    const float* z   = (const float*)d_in[0];
    const float* emb = (const float*)d_in[1];
    float* o = (float*)d_out;

    // workspace layout
    char* ws = (char*)d_ws;
    v8s*  af      = (v8s*)ws;                                      // 4 MB
    v8s*  ef      = (v8s*)(ws + 4194304);                          // 1 MB
    int*   idx     = (int*)(ws + 5242880);                         // 128 KB
    float* invn    = (float*)(ws + 5373952);                       // 32 KB
    int*   hist    = (int*)(ws + 5406720);                         // 32 KB
    float* partial = (float*)(ws + 5439488);                       // 2 KB

    float* out_q      = o;                  // 2097152 floats
    float* out_scal   = o + N_ELEM;         // loss, perplexity
    float* out_idxmap = o + N_ELEM + 2;     // 32768 floats

    // cmax: u16[128][32768] = 8 MB, cid-major. Prefer workspace if large
    // enough; otherwise the out_q region (8.39 MB needed, 8.51 MB available;
    // written by pass1, read by rescore, overwritten by gather_loss after).
    unsigned short* cmaxb;
    if (ws_size >= (size_t)5441536 + 8388608)
        cmaxb = (unsigned short*)(ws + 5441536);
    else
        cmaxb = (unsigned short*)o;

    hipMemsetAsync(hist, 0, NUM_EMBED * sizeof(int), stream);

    invnorm_kernel<<<NUM_EMBED / 4, 256, 0, stream>>>(emb, invn);
    en_frag_kernel<<<256, 256, 0, stream>>>(emb, invn, ef);
    z_prep_kernel<<<512, 256, 0, stream>>>(z, af);
    pass1_kernel<<<2048, 512, 0, stream>>>(af, ef, cmaxb);
    rescore_kernel<<<N_TOK / RS_TOK, 256, 0, stream>>>(cmaxb, z, emb, invn,
                                                       idx, out_idxmap);
    gather_loss_kernel<<<N_TOK / 64, 256, 0, stream>>>(z, emb, idx, out_q, partial, hist);
    finalize_kernel<<<1, 256, 0, stream>>>(partial, hist, out_scal);
}

// Round 11
// 267.627 us; speedup vs baseline: 1.2044x; 1.2044x over previous
//
#include <hip/hip_runtime.h>
#include <hip/hip_bf16.h>
#include <math.h>

// Problem constants
#define B_    8
#define C_    64
#define H_    64
#define W_    64
#define NUM_EMBED 8192
#define DIMS  64
#define N_TOK (B_ * H_ * W_)           // 32768
#define N_ELEM (B_ * C_ * H_ * W_)     // 2097152

typedef short v8s __attribute__((ext_vector_type(8)));   // 8 bf16 = 4 VGPR
typedef float v4f __attribute__((ext_vector_type(4)));   // MFMA acc

#define MARGIN 0.011f      // empirical bf16 margin, passed rounds 0-4
#define UB_ULP 0.008f      // max up-rounding of the u16 monotone bound

// ---- helpers ---------------------------------------------------------------
__device__ __forceinline__ short bf16_rne(float x) {
    unsigned u = __float_as_uint(x);
    unsigned r = (u + 0x7FFFu + ((u >> 16) & 1u)) >> 16;
    return (short)r;
}
// monotone float->u32 (order-preserving, incl. negatives)
__device__ __forceinline__ unsigned mono(float f) {
    int b = __float_as_int(f);
    return (unsigned)(b ^ ((b >> 31) | 0x80000000));
}
__device__ __forceinline__ float demono(unsigned u) {
    int b = (u >> 31) ? (int)(u ^ 0x80000000u) : (int)~u;
    return __int_as_float(b);
}
__device__ __forceinline__ unsigned short ub16(float x) {
    // 16-bit monotone upper bound (round UP)
    return (unsigned short)((mono(x) + 0xFFFFu) >> 16);
}

// ---------------------------------------------------------------------------
// P1: inverse row norms of embedding. 4 rows/block, one wave per row.
// ---------------------------------------------------------------------------
__global__ void invnorm_kernel(const float* __restrict__ emb, float* __restrict__ invn) {
    int wave = threadIdx.x >> 6;
    int lane = threadIdx.x & 63;
    int row  = blockIdx.x * 4 + wave;
    float v = emb[row * DIMS + lane];
    float s = v * v;
    #pragma unroll
    for (int off = 1; off < 64; off <<= 1) s += __shfl_xor(s, off, 64);
    if (lane == 0) invn[row] = 1.0f / sqrtf(s);
}

// ---------------------------------------------------------------------------
// P2: build B fragments: en_frag[(ct*2+st)*64 + lane] = 8 bf16 of
//     en[code = ct*16 + (lane&15)][k = st*32 + (lane>>4)*8 + j]
// ---------------------------------------------------------------------------
__global__ void en_frag_kernel(const float* __restrict__ emb, const float* __restrict__ invn,
                               v8s* __restrict__ ef) {
    int ch = blockIdx.x * 256 + threadIdx.x;      // 0..65535
    int l  = ch & 63;
    int st = (ch >> 6) & 1;
    int ct = ch >> 7;
    int code = ct * 16 + (l & 15);
    int kb   = st * 32 + ((l >> 4) & 3) * 8;
    float rn = invn[code];
    v8s o;
    #pragma unroll
    for (int j = 0; j < 8; ++j) o[j] = bf16_rne(emb[code * DIMS + kb + j] * rn);
    ef[ch] = o;
}

// ---------------------------------------------------------------------------
// P3: z -> A fragments (normalized bf16). Block = one (b,h) row = 64 tokens.
// ---------------------------------------------------------------------------
__global__ __launch_bounds__(256)
void z_prep_kernel(const float* __restrict__ z, v8s* __restrict__ af) {
    __shared__ float zs[64][65];   // [c][token_local], +1 pad
    __shared__ float part[4][64];
    __shared__ float rn[64];
    const int tid = threadIdx.x;
    const int w   = tid & 63;
    const int cg  = tid >> 6;
    const int bh  = blockIdx.x;            // 0..511
    const int b   = bh >> 6, h = bh & 63;

    const float* zb = z + (size_t)b * (C_ * H_ * W_) + h * W_;
    float ss = 0.f;
    #pragma unroll
    for (int cc = 0; cc < 16; ++cc) {
        int c = cg * 16 + cc;
        float v = zb[c * (H_ * W_) + w];
        zs[c][w] = v;
        ss += v * v;
    }
    part[cg][w] = ss;
    __syncthreads();
    if (tid < 64) {
        float s = part[0][tid] + part[1][tid] + part[2][tid] + part[3][tid];
        rn[tid] = 1.0f / sqrtf(s);
    }
    __syncthreads();

    // A fragments: 512 chunks (4 mtiles x 2 ksteps x 64 lanes), 2 per thread
    #pragma unroll
    for (int ii = 0; ii < 2; ++ii) {
        int ch  = tid + ii * 256;
        int mtl = ch >> 7;
        int st  = (ch >> 6) & 1;
        int l   = ch & 63;
        int tloc = mtl * 16 + (l & 15);
        int kb   = st * 32 + ((l >> 4) & 3) * 8;
        float rr = rn[tloc];
        v8s o;
        #pragma unroll
        for (int j = 0; j < 8; ++j) o[j] = bf16_rne(zs[kb + j][tloc] * rr);
        af[(size_t)((bh * 4 + mtl) * 2 + st) * 64 + l] = o;
    }
}

// ---------------------------------------------------------------------------
// GEMM config (pass1 = the only GEMM): unchanged from round 9 (RT=2, no
// spill, XCD-local bm, 16-way split, per-64-code upper-bound export).
// ---------------------------------------------------------------------------
#define RT 2
#define SPLITS 16
#define TILES_PER_BLOCK 32
#define CHUNK_TILES 8
#define CHUNKS (TILES_PER_BLOCK / CHUNK_TILES)   // 4
#define SUBT 4                          // tiles per bound group (64 codes)
#define NSUB (CHUNK_TILES / SUBT)       // 2 sub-chunks per LDS chunk
#define NCHUNK_TOT 128                  // 16 splits * 4 chunks * 2 sub = 128

__global__ __launch_bounds__(512, 8)
void pass1_kernel(const v8s* __restrict__ af, const v8s* __restrict__ ef,
                  unsigned short* __restrict__ cmax) {
    __shared__ v8s lds[CHUNK_TILES * 2 * 64];   // 16 KB
    const int tid  = threadIdx.x;
    const int lane = tid & 63;
    const int wave = tid >> 6;
    const int bm    = blockIdx.x & 127;         // low bits -> XCD locality
    const int split = blockIdx.x >> 7;
    const int tile0 = split * TILES_PER_BLOCK;

    const int mtb = bm * 16 + wave * RT;        // first m-tile of this wave
    v8s a[RT][2];
    #pragma unroll
    for (int r = 0; r < RT; ++r)
        #pragma unroll
        for (int s = 0; s < 2; ++s)
            a[r][s] = af[(size_t)((mtb + r) * 2 + s) * 64 + lane];

    const float4* gsrc = (const float4*)(ef + (size_t)tile0 * 2 * 64);
    float4* lf = (float4*)lds;
    float4 pre[2];
    pre[0] = gsrc[tid];
    pre[1] = gsrc[tid + 512];

    for (int c = 0; c < CHUNKS; ++c) {
        __syncthreads();
        lf[tid]       = pre[0];
        lf[tid + 512] = pre[1];
        if (c + 1 < CHUNKS) {
            const float4* nx = gsrc + (size_t)(c + 1) * 1024;
            pre[0] = nx[tid];
            pre[1] = nx[tid + 512];
        }
        __syncthreads();

        #pragma unroll
        for (int jj = 0; jj < NSUB; ++jj) {
            v4f mxc[RT];
            #pragma unroll
            for (int r = 0; r < RT; ++r)
                mxc[r] = (v4f){-1e30f, -1e30f, -1e30f, -1e30f};

            #pragma unroll
            for (int j4 = 0; j4 < SUBT; ++j4) {
                const int j = jj * SUBT + j4;
                v8s b0 = lds[(j * 2 + 0) * 64 + lane];
                v8s b1 = lds[(j * 2 + 1) * 64 + lane];
                #pragma unroll
                for (int r = 0; r < RT; ++r) {
                    v4f t = (v4f){0.f, 0.f, 0.f, 0.f};
                    t = __builtin_amdgcn_mfma_f32_16x16x32_bf16(a[r][0], b0, t, 0, 0, 0);
                    t = __builtin_amdgcn_mfma_f32_16x16x32_bf16(a[r][1], b1, t, 0, 0, 0);
                    mxc[r][0] = fmaxf(mxc[r][0], t[0]);
                    mxc[r][1] = fmaxf(mxc[r][1], t[1]);
                    mxc[r][2] = fmaxf(mxc[r][2], t[2]);
                    mxc[r][3] = fmaxf(mxc[r][3], t[3]);
                }
            }

            // sub-chunk end: reduce over 16 code columns, export upper bound
            #pragma unroll
            for (int r = 0; r < RT; ++r)
                #pragma unroll
                for (int i = 0; i < 4; ++i) {
                    float v = mxc[r][i];
                    v = fmaxf(v, __shfl_xor(v, 1, 64));
                    v = fmaxf(v, __shfl_xor(v, 2, 64));
                    v = fmaxf(v, __shfl_xor(v, 4, 64));
                    v = fmaxf(v, __shfl_xor(v, 8, 64));
                    mxc[r][i] = v;
                }
            if ((lane & 15) == 0) {
                const int q   = lane >> 4;
                const int cid = split * (CHUNKS * NSUB) + c * NSUB + jj;
                unsigned short* dst = cmax + (size_t)cid * N_TOK;
                #pragma unroll
                for (int r = 0; r < RT; ++r) {
                    ushort4 v;
                    v.x = ub16(mxc[r][0]);
                    v.y = ub16(mxc[r][1]);
                    v.z = ub16(mxc[r][2]);
                    v.w = ub16(mxc[r][3]);
                    // tokens (mtb+r)*16 + q*4 + {0..3}: one 8 B store
                    *(ushort4*)(dst + (mtb + r) * 16 + q * 4) = v;
                }
            }
        }
    }
}

// ---------------------------------------------------------------------------
// Rescore v3: block = 8 tokens, 512 threads = 8 waves, ONE TOKEN PER WAVE.
// Round-10 lesson: v2's 8-tokens-serial-per-wave cut wave count 8x and
// occupancy to 24% -> latency exposed (163 us despite 21 MB traffic).
// v3 restores round-9's 32768 waves (TLP) and keeps v2's coalesced staging:
//   - z slab [64 c][8 w]: thread (c=tid>>3, w=tid&7) -> dense 32 B segments
//   - bounds [128 cid][8 t]: thread (cid=tid>>2, pair=tid&3) ushort2 loads
// Qualify + exact fp32 rescore loop unchanged (proven since round 4).
// ---------------------------------------------------------------------------
#define RS_TOK 8

__global__ __launch_bounds__(512)
void rescore_kernel(const unsigned short* __restrict__ cmax,
                    const float* __restrict__ z,
                    const float* __restrict__ emb,
                    const float* __restrict__ invn,
                    int* __restrict__ idx, float* __restrict__ idxmap) {
    __shared__ float zsh[64][9];             // [c][w], pad 9
    __shared__ unsigned short cms[128][10];  // [cid][t], pad 10
    const int tid  = threadIdx.x;
    const int lane = tid & 63;
    const int wv   = tid >> 6;               // 0..7 = local token
    const int tok0 = blockIdx.x * RS_TOK;
    const int bh   = tok0 >> 6;
    const int b    = bh >> 6, h = bh & 63;
    const int w0   = tok0 & 63;

    // stage z: 64 channels x 8 w (dense 32 B per channel segment)
    {
        const float* zb = z + (size_t)b * (C_ * H_ * W_) + h * W_ + w0;
        const int c = tid >> 3;
        const int w = tid & 7;
        zsh[c][w] = zb[c * (H_ * W_) + w];
    }
    // stage bounds: 128 cids x 8 tokens (16 B contiguous per cid)
    {
        const int cid  = tid >> 2;
        const int pair = tid & 3;
        const ushort2 v = *(const ushort2*)(cmax + (size_t)cid * N_TOK + tok0 + 2 * pair);
        cms[cid][2 * pair]     = v.x;
        cms[cid][2 * pair + 1] = v.y;
    }
    __syncthreads();

    const int token = tok0 + wv;
    const int g  = lane >> 4;      // row-group 0..3
    const int li = lane & 15;

    // per-token qualification (lane = cid, cid+64)
    float ub0 = demono(((unsigned)cms[lane][wv]) << 16);
    float ub1 = demono(((unsigned)cms[64 + lane][wv]) << 16);
    float m = fmaxf(ub0, ub1);
    #pragma unroll
    for (int off = 1; off < 64; off <<= 1) m = fmaxf(m, __shfl_xor(m, off, 64));
    const float thrf = m - (MARGIN + UB_ULP);
    unsigned long long q0 = __ballot(ub0 >= thrf);
    unsigned long long q1 = __ballot(ub1 >= thrf);

    // zr: lane's 4 channels of this token, from LDS
    float4 zr;
    zr.x = zsh[li * 4 + 0][wv];
    zr.y = zsh[li * 4 + 1][wv];
    zr.z = zsh[li * 4 + 2][wv];
    zr.w = zsh[li * 4 + 3][wv];

    float bv = -1e30f;
    int   bc = 0x7FFFFFFF;
    #pragma unroll
    for (int half = 0; half < 2; ++half) {
        unsigned long long q = half ? q1 : q0;
        const int cb = half ? 64 : 0;
        while (q) {
            const int cid = cb + (__ffsll(q) - 1);
            q &= q - 1;
            const int rbase = cid * 64;       // first code of sub-chunk
            #pragma unroll
            for (int i = 0; i < 16; ++i) {
                const int code = rbase + i * 4 + g;
                const float4 e = ((const float4*)(emb + (size_t)code * DIMS))[li];
                float s = zr.x * e.x;
                s = fmaf(zr.y, e.y, s);
                s = fmaf(zr.z, e.z, s);
                s = fmaf(zr.w, e.w, s);
                s += __shfl_xor(s, 1, 64);
                s += __shfl_xor(s, 2, 64);
                s += __shfl_xor(s, 4, 64);
                s += __shfl_xor(s, 8, 64);
                const float val = s * invn[code];
                if (val > bv || (val == bv && code < bc)) { bv = val; bc = code; }
            }
        }
    }
    // merge the 4 row-groups (16-lane groups already agree)
    #pragma unroll
    for (int off = 1; off < 64; off <<= 1) {
        float ov = __shfl_xor(bv, off, 64);
        int   oc = __shfl_xor(bc, off, 64);
        if (ov > bv || (ov == bv && oc < bc)) { bv = ov; bc = oc; }
    }
    if (lane == 0) {
        idx[token]    = bc;
        idxmap[token] = (float)bc;
    }
}

// ---------------------------------------------------------------------------
// K3: gather z_q, out = zv + (q - zv), SSE partial, histogram.
// Emb rows staged via LDS (wave-uniform id -> coalesced row loads).
// ---------------------------------------------------------------------------
__global__ void gather_loss_kernel(const float* __restrict__ z,
                                   const float* __restrict__ emb,
                                   const int* __restrict__ idx,
                                   float* __restrict__ out,
                                   float* __restrict__ partial,
                                   int* __restrict__ hist) {
    __shared__ float eld[64][65];
    __shared__ float red[256];
    const int tid  = threadIdx.x;
    const int lane = tid & 63;   // w
    const int wave = tid >> 6;
    const int bt   = blockIdx.x; // 0..511
    const int b    = bt >> 6;
    const int h    = bt & 63;

    // stage emb rows of this block's 64 tokens (16 per wave, coalesced rows)
    for (int i = 0; i < 16; ++i) {
        const int tl = wave * 16 + i;
        const int id = idx[bt * 64 + tl];
        eld[tl][lane] = emb[(size_t)id * DIMS + lane];
    }
    __syncthreads();

    const long base = (long)b * (C_ * H_ * W_) + h * W_ + lane;

    float sse = 0.f;
    #pragma unroll
    for (int cc = 0; cc < 16; ++cc) {
        const int c = wave * 16 + cc;
        const float q  = eld[lane][c];
        const float zv = z[base + (long)c * (H_ * W_)];
        out[base + (long)c * (H_ * W_)] = zv + (q - zv);  // exact ref expression
        const float d = q - zv;
        sse += d * d;
    }

    red[tid] = sse;
    __syncthreads();
    for (int s = 128; s > 0; s >>= 1) {
        if (tid < s) red[tid] += red[tid + s];
        __syncthreads();
    }
    if (tid == 0) partial[bt] = red[0];
    if (wave == 0) atomicAdd(&hist[idx[bt * 64 + lane]], 1);
}

// ---------------------------------------------------------------------------
// K4: finalize loss + perplexity. One block of 256 threads.
// ---------------------------------------------------------------------------
__global__ void finalize_kernel(const float* __restrict__ partial,
                                const int* __restrict__ hist,
                                float* __restrict__ out_scal) {
    __shared__ double red[256];
    const int tid = threadIdx.x;

    double s = 0.0;
    for (int i = tid; i < 512; i += 256) s += (double)partial[i];
    red[tid] = s;
    __syncthreads();
    for (int st = 128; st > 0; st >>= 1) {
        if (tid < st) red[tid] += red[tid + st];
        __syncthreads();
    }
    const double sse = red[0];
    __syncthreads();

    double e = 0.0;
    for (int k = tid; k < NUM_EMBED; k += 256) {
        float p = (float)hist[k] / (float)N_TOK;
        e += (double)(p * logf(p + 1e-10f));
    }
    red[tid] = e;
    __syncthreads();
    for (int st = 128; st > 0; st >>= 1) {
        if (tid < st) red[tid] += red[tid + st];
        __syncthreads();
    }
    if (tid == 0) {
        out_scal[0] = (float)(1.25 * sse / (double)N_ELEM);
        out_scal[1] = expf(-(float)red[0]);
    }
}

// ---------------------------------------------------------------------------
extern "C" void kernel_launch(void* const* d_in, const int* in_sizes, int n_in,
                              void* d_out, int out_size, void* d_ws, size_t ws_size,
                              hipStream_t stream) {
    const float* z   = (const float*)d_in[0];
    const float* emb = (const float*)d_in[1];
    float* o = (float*)d_out;

    // workspace layout
    char* ws = (char*)d_ws;
    v8s*  af      = (v8s*)ws;                                      // 4 MB
    v8s*  ef      = (v8s*)(ws + 4194304);                          // 1 MB
    int*   idx     = (int*)(ws + 5242880);                         // 128 KB
    float* invn    = (float*)(ws + 5373952);                       // 32 KB
    int*   hist    = (int*)(ws + 5406720);                         // 32 KB
    float* partial = (float*)(ws + 5439488);                       // 2 KB

    float* out_q      = o;                  // 2097152 floats
    float* out_scal   = o + N_ELEM;         // loss, perplexity
    float* out_idxmap = o + N_ELEM + 2;     // 32768 floats

    // cmax: u16[128][32768] = 8 MB, cid-major. Prefer workspace if large
    // enough; otherwise the out_q region (8.39 MB needed, 8.51 MB available;
    // written by pass1, read by rescore, overwritten by gather_loss after).
    unsigned short* cmaxb;
    if (ws_size >= (size_t)5441536 + 8388608)
        cmaxb = (unsigned short*)(ws + 5441536);
    else
        cmaxb = (unsigned short*)o;

    hipMemsetAsync(hist, 0, NUM_EMBED * sizeof(int), stream);

    invnorm_kernel<<<NUM_EMBED / 4, 256, 0, stream>>>(emb, invn);
    en_frag_kernel<<<256, 256, 0, stream>>>(emb, invn, ef);
    z_prep_kernel<<<512, 256, 0, stream>>>(z, af);
    pass1_kernel<<<2048, 512, 0, stream>>>(af, ef, cmaxb);
    rescore_kernel<<<N_TOK / RS_TOK, 512, 0, stream>>>(cmaxb, z, emb, invn,
                                                       idx, out_idxmap);
    gather_loss_kernel<<<N_TOK / 64, 256, 0, stream>>>(z, emb, idx, out_q, partial, hist);
    finalize_kernel<<<1, 256, 0, stream>>>(partial, hist, out_scal);
}

// Round 12
// 257.120 us; speedup vs baseline: 1.2536x; 1.0409x over previous
//
#include <hip/hip_runtime.h>
#include <hip/hip_bf16.h>
#include <math.h>

// Problem constants
#define B_    8
#define C_    64
#define H_    64
#define W_    64
#define NUM_EMBED 8192
#define DIMS  64
#define N_TOK (B_ * H_ * W_)           // 32768
#define N_ELEM (B_ * C_ * H_ * W_)     // 2097152

typedef short v8s __attribute__((ext_vector_type(8)));   // 8 bf16 = 4 VGPR
typedef float v4f __attribute__((ext_vector_type(4)));   // MFMA acc

#define MARGIN 0.011f      // empirical bf16 margin, passed rounds 0-4
#define UB_ULP 0.008f      // max up-rounding of the u16 monotone bound

// ---- helpers ---------------------------------------------------------------
__device__ __forceinline__ short bf16_rne(float x) {
    unsigned u = __float_as_uint(x);
    unsigned r = (u + 0x7FFFu + ((u >> 16) & 1u)) >> 16;
    return (short)r;
}
// monotone float->u32 (order-preserving, incl. negatives)
__device__ __forceinline__ unsigned mono(float f) {
    int b = __float_as_int(f);
    return (unsigned)(b ^ ((b >> 31) | 0x80000000));
}
__device__ __forceinline__ float demono(unsigned u) {
    int b = (u >> 31) ? (int)(u ^ 0x80000000u) : (int)~u;
    return __int_as_float(b);
}
__device__ __forceinline__ unsigned short ub16(float x) {
    // 16-bit monotone upper bound (round UP)
    return (unsigned short)((mono(x) + 0xFFFFu) >> 16);
}

// ---------------------------------------------------------------------------
// P1: inverse row norms of embedding. 4 rows/block, one wave per row.
// ---------------------------------------------------------------------------
__global__ void invnorm_kernel(const float* __restrict__ emb, float* __restrict__ invn) {
    int wave = threadIdx.x >> 6;
    int lane = threadIdx.x & 63;
    int row  = blockIdx.x * 4 + wave;
    float v = emb[row * DIMS + lane];
    float s = v * v;
    #pragma unroll
    for (int off = 1; off < 64; off <<= 1) s += __shfl_xor(s, off, 64);
    if (lane == 0) invn[row] = 1.0f / sqrtf(s);
}

// ---------------------------------------------------------------------------
// P2: build B fragments: en_frag[(ct*2+st)*64 + lane] = 8 bf16 of
//     en[code = ct*16 + (lane&15)][k = st*32 + (lane>>4)*8 + j]
// ---------------------------------------------------------------------------
__global__ void en_frag_kernel(const float* __restrict__ emb, const float* __restrict__ invn,
                               v8s* __restrict__ ef) {
    int ch = blockIdx.x * 256 + threadIdx.x;      // 0..65535
    int l  = ch & 63;
    int st = (ch >> 6) & 1;
    int ct = ch >> 7;
    int code = ct * 16 + (l & 15);
    int kb   = st * 32 + ((l >> 4) & 3) * 8;
    float rn = invn[code];
    v8s o;
    #pragma unroll
    for (int j = 0; j < 8; ++j) o[j] = bf16_rne(emb[code * DIMS + kb + j] * rn);
    ef[ch] = o;
}

// ---------------------------------------------------------------------------
// P3: z -> A fragments (normalized bf16) + z_tok (token-major fp32 copy for
// the exact rescore; round-11 lesson: rescore reading z channel-strided was
// 2-4x line-amplified). Block = one (b,h) row = 64 tokens.
// ---------------------------------------------------------------------------
__global__ __launch_bounds__(256)
void z_prep_kernel(const float* __restrict__ z, v8s* __restrict__ af,
                   float* __restrict__ z_tok) {
    __shared__ float zs[64][65];   // [c][token_local], +1 pad
    __shared__ float part[4][64];
    __shared__ float rn[64];
    const int tid = threadIdx.x;
    const int w   = tid & 63;
    const int cg  = tid >> 6;
    const int bh  = blockIdx.x;            // 0..511
    const int b   = bh >> 6, h = bh & 63;

    const float* zb = z + (size_t)b * (C_ * H_ * W_) + h * W_;
    float ss = 0.f;
    #pragma unroll
    for (int cc = 0; cc < 16; ++cc) {
        int c = cg * 16 + cc;
        float v = zb[c * (H_ * W_) + w];
        zs[c][w] = v;
        ss += v * v;
    }
    part[cg][w] = ss;
    __syncthreads();
    if (tid < 64) {
        float s = part[0][tid] + part[1][tid] + part[2][tid] + part[3][tid];
        rn[tid] = 1.0f / sqrtf(s);
    }
    __syncthreads();

    // z_tok[t][c], coalesced in c
    {
        int c  = tid & 63;
        int tg = tid >> 6;
        #pragma unroll
        for (int i = 0; i < 16; ++i) {
            int tloc = tg * 16 + i;
            z_tok[(size_t)(bh * 64 + tloc) * DIMS + c] = zs[c][tloc];
        }
    }
    // A fragments: 512 chunks (4 mtiles x 2 ksteps x 64 lanes), 2 per thread
    #pragma unroll
    for (int ii = 0; ii < 2; ++ii) {
        int ch  = tid + ii * 256;
        int mtl = ch >> 7;
        int st  = (ch >> 6) & 1;
        int l   = ch & 63;
        int tloc = mtl * 16 + (l & 15);
        int kb   = st * 32 + ((l >> 4) & 3) * 8;
        float rr = rn[tloc];
        v8s o;
        #pragma unroll
        for (int j = 0; j < 8; ++j) o[j] = bf16_rne(zs[kb + j][tloc] * rr);
        af[(size_t)((bh * 4 + mtl) * 2 + st) * 64 + l] = o;
    }
}

// ---------------------------------------------------------------------------
// GEMM config (pass1 = the only GEMM):
//  - 256 threads (4 waves), RT=4 m-tiles/wave -> block M = 256 tokens
//    (round-11 lesson: RT=2 doubled ds_read per MFMA; round-8 lesson: RT=4
//    at a 64-VGPR cap spills -> use launch_bounds(256,4) = 128-VGPR cap,
//    live state ~90 regs, no spill, ~24 waves/CU)
//  - codes split 16-way: block streams 512 codes = 32 tiles of 16
//  - chunks of 8 tiles staged in 16 KB LDS, 4 chunks
//  - per SUB-chunk of 4 tiles (64 codes), export per-token upper bound
//  - cmax layout v2, BLOCK-MAJOR: cmax[tokblk=token>>3][cid][token&7]
//    -> a rescore 8-token group's 128x8 bounds are one contiguous 2 KB
//  - grid = 128 bm x 16 splits = 2048 blocks, bm in LOW bits (XCD-local)
// ---------------------------------------------------------------------------
#define RT 4
#define SPLITS 16
#define TILES_PER_BLOCK 32
#define CHUNK_TILES 8
#define CHUNKS (TILES_PER_BLOCK / CHUNK_TILES)   // 4
#define SUBT 4                          // tiles per bound group (64 codes)
#define NSUB (CHUNK_TILES / SUBT)       // 2 sub-chunks per LDS chunk
#define NCHUNK_TOT 128                  // 16 splits * 4 chunks * 2 sub = 128

__global__ __launch_bounds__(256, 4)
void pass1_kernel(const v8s* __restrict__ af, const v8s* __restrict__ ef,
                  unsigned short* __restrict__ cmax) {
    __shared__ v8s lds[CHUNK_TILES * 2 * 64];   // 16 KB
    const int tid  = threadIdx.x;
    const int lane = tid & 63;
    const int wave = tid >> 6;                  // 0..3
    const int bm    = blockIdx.x & 127;         // low bits -> XCD locality
    const int split = blockIdx.x >> 7;
    const int tile0 = split * TILES_PER_BLOCK;

    const int mtb = bm * 16 + wave * RT;        // first m-tile of this wave
    v8s a[RT][2];
    #pragma unroll
    for (int r = 0; r < RT; ++r)
        #pragma unroll
        for (int s = 0; s < 2; ++s)
            a[r][s] = af[(size_t)((mtb + r) * 2 + s) * 64 + lane];

    const float4* gsrc = (const float4*)(ef + (size_t)tile0 * 2 * 64); // 4096 f4
    float4* lf = (float4*)lds;
    float4 pre[4];
    #pragma unroll
    for (int i = 0; i < 4; ++i) pre[i] = gsrc[tid + i * 256];

    for (int c = 0; c < CHUNKS; ++c) {
        __syncthreads();
        #pragma unroll
        for (int i = 0; i < 4; ++i) lf[tid + i * 256] = pre[i];
        if (c + 1 < CHUNKS) {
            const float4* nx = gsrc + (size_t)(c + 1) * 1024;
            #pragma unroll
            for (int i = 0; i < 4; ++i) pre[i] = nx[tid + i * 256];
        }
        __syncthreads();

        #pragma unroll
        for (int jj = 0; jj < NSUB; ++jj) {
            v4f mxc[RT];
            #pragma unroll
            for (int r = 0; r < RT; ++r)
                mxc[r] = (v4f){-1e30f, -1e30f, -1e30f, -1e30f};

            #pragma unroll
            for (int j4 = 0; j4 < SUBT; ++j4) {
                const int j = jj * SUBT + j4;
                v8s b0 = lds[(j * 2 + 0) * 64 + lane];
                v8s b1 = lds[(j * 2 + 1) * 64 + lane];
                #pragma unroll
                for (int r = 0; r < RT; ++r) {
                    v4f t = (v4f){0.f, 0.f, 0.f, 0.f};
                    t = __builtin_amdgcn_mfma_f32_16x16x32_bf16(a[r][0], b0, t, 0, 0, 0);
                    t = __builtin_amdgcn_mfma_f32_16x16x32_bf16(a[r][1], b1, t, 0, 0, 0);
                    mxc[r][0] = fmaxf(mxc[r][0], t[0]);
                    mxc[r][1] = fmaxf(mxc[r][1], t[1]);
                    mxc[r][2] = fmaxf(mxc[r][2], t[2]);
                    mxc[r][3] = fmaxf(mxc[r][3], t[3]);
                }
            }

            // sub-chunk end: reduce over 16 code columns, export upper bound
            #pragma unroll
            for (int r = 0; r < RT; ++r)
                #pragma unroll
                for (int i = 0; i < 4; ++i) {
                    float v = mxc[r][i];
                    v = fmaxf(v, __shfl_xor(v, 1, 64));
                    v = fmaxf(v, __shfl_xor(v, 2, 64));
                    v = fmaxf(v, __shfl_xor(v, 4, 64));
                    v = fmaxf(v, __shfl_xor(v, 8, 64));
                    mxc[r][i] = v;
                }
            if ((lane & 15) == 0) {
                const int q   = lane >> 4;
                const int cid = split * (CHUNKS * NSUB) + c * NSUB + jj;
                #pragma unroll
                for (int r = 0; r < RT; ++r) {
                    ushort4 v;
                    v.x = ub16(mxc[r][0]);
                    v.y = ub16(mxc[r][1]);
                    v.z = ub16(mxc[r][2]);
                    v.w = ub16(mxc[r][3]);
                    // tokens (mtb+r)*16 + q*4 + {0..3} -> block-major slot
                    const int blk = (mtb + r) * 2 + (q >> 1);
                    *(ushort4*)(cmax + (size_t)blk * 1024 + cid * 8 + (q & 1) * 4) = v;
                }
            }
        }
    }
}

// ---------------------------------------------------------------------------
// Rescore v4: NO LDS, NO BARRIERS. 256 threads = 4 waves, one token/wave,
// grid 8192. Round-11 lesson: staging gathers (cmax 64KB-stride, z 16KB-
// stride) were 3.5x line-amplified -> 550 GB/s effective. Now:
//   - bounds: block-major cmax -> wave reads its token's 128 bounds from a
//     contiguous 2 KB region (shared with 7 neighbor tokens, L1/L2-hot)
//   - z: z_tok row = one coalesced float4/lane load
// Qualify + exact fp32 rescore loop unchanged (proven since round 4).
// ---------------------------------------------------------------------------
__global__ __launch_bounds__(256)
void rescore_kernel(const unsigned short* __restrict__ cmax,
                    const float* __restrict__ z_tok,
                    const float* __restrict__ emb,
                    const float* __restrict__ invn,
                    int* __restrict__ idx, float* __restrict__ idxmap) {
    const int tid   = threadIdx.x;
    const int lane  = tid & 63;
    const int wv    = tid >> 6;
    const int token = blockIdx.x * 4 + wv;
    const int tokblk = token >> 3;
    const int sub    = token & 7;

    const unsigned short* cb_ = cmax + (size_t)tokblk * 1024 + sub;
    float ub0 = demono(((unsigned)cb_[lane * 8]) << 16);
    float ub1 = demono(((unsigned)cb_[(64 + lane) * 8]) << 16);

    // wave-max of the 128 upper bounds -> threshold
    float m = fmaxf(ub0, ub1);
    #pragma unroll
    for (int off = 1; off < 64; off <<= 1) m = fmaxf(m, __shfl_xor(m, off, 64));
    const float thrf = m - (MARGIN + UB_ULP);
    unsigned long long q0 = __ballot(ub0 >= thrf);
    unsigned long long q1 = __ballot(ub1 >= thrf);

    const int g  = lane >> 4;      // row-group 0..3
    const int li = lane & 15;
    const float4 zr = ((const float4*)(z_tok + (size_t)token * DIMS))[li];

    float bv = -1e30f;
    int   bc = 0x7FFFFFFF;
    #pragma unroll
    for (int half = 0; half < 2; ++half) {
        unsigned long long q = half ? q1 : q0;
        const int cb = half ? 64 : 0;
        while (q) {
            const int cid = cb + (__ffsll(q) - 1);
            q &= q - 1;
            const int rbase = cid * 64;       // first code of sub-chunk
            #pragma unroll
            for (int i = 0; i < 16; ++i) {
                const int code = rbase + i * 4 + g;
                const float4 e = ((const float4*)(emb + (size_t)code * DIMS))[li];
                float s = zr.x * e.x;
                s = fmaf(zr.y, e.y, s);
                s = fmaf(zr.z, e.z, s);
                s = fmaf(zr.w, e.w, s);
                s += __shfl_xor(s, 1, 64);
                s += __shfl_xor(s, 2, 64);
                s += __shfl_xor(s, 4, 64);
                s += __shfl_xor(s, 8, 64);
                const float val = s * invn[code];
                if (val > bv || (val == bv && code < bc)) { bv = val; bc = code; }
            }
        }
    }
    // merge the 4 row-groups (16-lane groups already agree)
    #pragma unroll
    for (int off = 1; off < 64; off <<= 1) {
        float ov = __shfl_xor(bv, off, 64);
        int   oc = __shfl_xor(bc, off, 64);
        if (ov > bv || (ov == bv && oc < bc)) { bv = ov; bc = oc; }
    }
    if (lane == 0) {
        idx[token]    = bc;
        idxmap[token] = (float)bc;
    }
}

// ---------------------------------------------------------------------------
// K3: gather z_q, out = zv + (q - zv), SSE partial, histogram.
// Emb rows staged via LDS (wave-uniform id -> coalesced row loads).
// ---------------------------------------------------------------------------
__global__ void gather_loss_kernel(const float* __restrict__ z,
                                   const float* __restrict__ emb,
                                   const int* __restrict__ idx,
                                   float* __restrict__ out,
                                   float* __restrict__ partial,
                                   int* __restrict__ hist) {
    __shared__ float eld[64][65];
    __shared__ float red[256];
    const int tid  = threadIdx.x;
    const int lane = tid & 63;   // w
    const int wave = tid >> 6;
    const int bt   = blockIdx.x; // 0..511
    const int b    = bt >> 6;
    const int h    = bt & 63;

    // stage emb rows of this block's 64 tokens (16 per wave, coalesced rows)
    for (int i = 0; i < 16; ++i) {
        const int tl = wave * 16 + i;
        const int id = idx[bt * 64 + tl];
        eld[tl][lane] = emb[(size_t)id * DIMS + lane];
    }
    __syncthreads();

    const long base = (long)b * (C_ * H_ * W_) + h * W_ + lane;

    float sse = 0.f;
    #pragma unroll
    for (int cc = 0; cc < 16; ++cc) {
        const int c = wave * 16 + cc;
        const float q  = eld[lane][c];
        const float zv = z[base + (long)c * (H_ * W_)];
        out[base + (long)c * (H_ * W_)] = zv + (q - zv);  // exact ref expression
        const float d = q - zv;
        sse += d * d;
    }

    red[tid] = sse;
    __syncthreads();
    for (int s = 128; s > 0; s >>= 1) {
        if (tid < s) red[tid] += red[tid + s];
        __syncthreads();
    }
    if (tid == 0) partial[bt] = red[0];
    if (wave == 0) atomicAdd(&hist[idx[bt * 64 + lane]], 1);
}

// ---------------------------------------------------------------------------
// K4: finalize loss + perplexity. One block of 256 threads.
// ---------------------------------------------------------------------------
__global__ void finalize_kernel(const float* __restrict__ partial,
                                const int* __restrict__ hist,
                                float* __restrict__ out_scal) {
    __shared__ double red[256];
    const int tid = threadIdx.x;

    double s = 0.0;
    for (int i = tid; i < 512; i += 256) s += (double)partial[i];
    red[tid] = s;
    __syncthreads();
    for (int st = 128; st > 0; st >>= 1) {
        if (tid < st) red[tid] += red[tid + st];
        __syncthreads();
    }
    const double sse = red[0];
    __syncthreads();

    double e = 0.0;
    for (int k = tid; k < NUM_EMBED; k += 256) {
        float p = (float)hist[k] / (float)N_TOK;
        e += (double)(p * logf(p + 1e-10f));
    }
    red[tid] = e;
    __syncthreads();
    for (int st = 128; st > 0; st >>= 1) {
        if (tid < st) red[tid] += red[tid + st];
        __syncthreads();
    }
    if (tid == 0) {
        out_scal[0] = (float)(1.25 * sse / (double)N_ELEM);
        out_scal[1] = expf(-(float)red[0]);
    }
}

// ---------------------------------------------------------------------------
extern "C" void kernel_launch(void* const* d_in, const int* in_sizes, int n_in,
                              void* d_out, int out_size, void* d_ws, size_t ws_size,
                              hipStream_t stream) {
    const float* z   = (const float*)d_in[0];
    const float* emb = (const float*)d_in[1];
    float* o = (float*)d_out;

    // workspace layout (~22.3 MB; ws proven ~268 MB by the harness's fill)
    char* ws = (char*)d_ws;
    v8s*  af      = (v8s*)ws;                                      // 4 MB
    v8s*  ef      = (v8s*)(ws + 4194304);                          // 1 MB
    float* z_tok  = (float*)(ws + 5242880);                        // 8 MB
    unsigned short* cmaxb = (unsigned short*)(ws + 13631488);      // 8 MB
    int*   idx     = (int*)(ws + 22020096);                        // 128 KB
    float* invn    = (float*)(ws + 22151168);                      // 32 KB
    int*   hist    = (int*)(ws + 22183936);                        // 32 KB
    float* partial = (float*)(ws + 22216704);                      // 2 KB

    float* out_q      = o;                  // 2097152 floats
    float* out_scal   = o + N_ELEM;         // loss, perplexity
    float* out_idxmap = o + N_ELEM + 2;     // 32768 floats

    hipMemsetAsync(hist, 0, NUM_EMBED * sizeof(int), stream);

    invnorm_kernel<<<NUM_EMBED / 4, 256, 0, stream>>>(emb, invn);
    en_frag_kernel<<<256, 256, 0, stream>>>(emb, invn, ef);
    z_prep_kernel<<<512, 256, 0, stream>>>(z, af, z_tok);
    pass1_kernel<<<2048, 256, 0, stream>>>(af, ef, cmaxb);
    rescore_kernel<<<N_TOK / 4, 256, 0, stream>>>(cmaxb, z_tok, emb, invn,
                                                  idx, out_idxmap);
    gather_loss_kernel<<<N_TOK / 64, 256, 0, stream>>>(z, emb, idx, out_q, partial, hist);
    finalize_kernel<<<1, 256, 0, stream>>>(partial, hist, out_scal);
}